// Round 1
// baseline (86.673 us; speedup 1.0000x reference)
//
#include <hip/hip_runtime.h>
#include <hip/hip_bf16.h>

// Problem constants (from reference setup_inputs)
#define B_N    4096      // batch
#define D_K    1024      // feature dim
#define MARGIN 0.3f
#define BIGM   1e5f

typedef __attribute__((ext_vector_type(8))) short short8;
typedef __attribute__((ext_vector_type(4))) float f32x4;

__device__ inline ushort f2bf(float f) {
    unsigned u = __float_as_uint(f);
    unsigned r = (u + 0x7fffu + ((u >> 16) & 1u)) >> 16;
    return (ushort)r;
}

__device__ inline void async16(const ushort* g, ushort* l) {
    __builtin_amdgcn_global_load_lds(
        (const __attribute__((address_space(1))) void*)g,
        (__attribute__((address_space(3))) void*)l,
        16, 0, 0);
}

// Convert rows to bf16 (optionally gathered via ids) and compute fp32 squared norms.
__global__ void prep_rows(const float* __restrict__ src,
                          const int* __restrict__ gather_id,
                          ushort* __restrict__ dstB,
                          float* __restrict__ sq) {
    int row = blockIdx.x;
    int srow = gather_id ? gather_id[row] : row;
    const float4* s4 = (const float4*)(src + (size_t)srow * D_K);
    int t = threadIdx.x;                       // 256 threads, 4 floats each
    float4 v = s4[t];
    float ss = v.x * v.x + v.y * v.y + v.z * v.z + v.w * v.w;
    ushort4 b;
    b.x = f2bf(v.x); b.y = f2bf(v.y); b.z = f2bf(v.z); b.w = f2bf(v.w);
    ((ushort4*)(dstB + (size_t)row * D_K))[t] = b;

    // block reduce ss
    int lane = t & 63, w = t >> 6;
    #pragma unroll
    for (int o = 1; o < 64; o <<= 1) ss += __shfl_xor(ss, o);
    __shared__ float red[4];
    if (lane == 0) red[w] = ss;
    __syncthreads();
    if (t == 0) sq[row] = red[0] + red[1] + red[2] + red[3];
}

__global__ void init_minmax(int* __restrict__ maxb, int* __restrict__ minb) {
    int i = blockIdx.x * blockDim.x + threadIdx.x;
    if (i < B_N) { maxb[i] = 0; minb[i] = 0x7F800000; }  // 0.0f and +inf
}

// Fused 128x128-tile bf16 MFMA GEMM + distance + masked per-row max/min.
__global__ __launch_bounds__(256)
void dist_kernel(const ushort* __restrict__ A, const ushort* __restrict__ Bm,
                 const float* __restrict__ sqa, const float* __restrict__ sqb,
                 const int* __restrict__ ids,
                 int* __restrict__ maxb, int* __restrict__ minb) {
    __shared__ ushort lA[128 * 32];
    __shared__ ushort lB[128 * 32];

    const int t = threadIdx.x;
    const int lane = t & 63;
    const int wid = t >> 6;           // 4 waves
    const int wr = wid >> 1;          // wave row (0..1)
    const int wc = wid & 1;           // wave col (0..1)
    const int rb = blockIdx.y;        // row tile
    const int cb = blockIdx.x;        // col tile
    const size_t arow0 = (size_t)rb * 128;
    const size_t brow0 = (size_t)cb * 128;

    // Staging: each wave stages 2 KiB of each tile (2 calls x 64 lanes x 16 B)
    int sidx0 = wid * 1024 + lane * 8;          // element index in 128x32 tile
    int r0 = sidx0 >> 5, c0 = sidx0 & 31;
    int sidx1 = sidx0 + 512;
    int r1 = sidx1 >> 5, c1 = sidx1 & 31;
    const ushort* gA0 = A + (arow0 + r0) * D_K + c0;
    const ushort* gA1 = A + (arow0 + r1) * D_K + c1;
    const ushort* gB0 = Bm + (brow0 + r0) * D_K + c0;
    const ushort* gB1 = Bm + (brow0 + r1) * D_K + c1;
    ushort* lA_w = lA + wid * 1024;   // wave-uniform LDS base
    ushort* lB_w = lB + wid * 1024;

    f32x4 acc[4][4] = {};

    for (int k0 = 0; k0 < D_K; k0 += 32) {
        async16(gA0 + k0, lA_w);
        async16(gA1 + k0, lA_w + 512);
        async16(gB0 + k0, lB_w);
        async16(gB1 + k0, lB_w + 512);
        __syncthreads();   // drains vmcnt(0) then barrier -> tiles visible

        short8 af[4], bfr[4];
        #pragma unroll
        for (int m = 0; m < 4; m++) {
            int row = wr * 64 + m * 16 + (lane & 15);
            af[m] = *(const short8*)&lA[row * 32 + (lane >> 4) * 8];
        }
        #pragma unroll
        for (int n = 0; n < 4; n++) {
            int row = wc * 64 + n * 16 + (lane & 15);
            bfr[n] = *(const short8*)&lB[row * 32 + (lane >> 4) * 8];
        }
        #pragma unroll
        for (int m = 0; m < 4; m++)
            #pragma unroll
            for (int n = 0; n < 4; n++)
                acc[m][n] = __builtin_amdgcn_mfma_f32_16x16x32_bf16(
                    af[m], bfr[n], acc[m][n], 0, 0, 0);

        __syncthreads();   // all reads done before next stage overwrites
    }

    // Epilogue: dist + masks + per-row max/min over this block's 128 cols.
    int colg[4]; float sb[4]; int idb[4];
    #pragma unroll
    for (int n = 0; n < 4; n++) {
        int c = cb * 128 + wc * 64 + n * 16 + (lane & 15);
        colg[n] = c; sb[n] = sqb[c]; idb[n] = ids[c];
    }
    #pragma unroll
    for (int m = 0; m < 4; m++) {
        #pragma unroll
        for (int r = 0; r < 4; r++) {
            int row = rb * 128 + wr * 64 + m * 16 + (lane >> 4) * 4 + r;
            float sa = sqa[row];
            int ida = ids[row];
            float mx = 0.0f, mn = 3.0e38f;
            #pragma unroll
            for (int n = 0; n < 4; n++) {
                float s2 = sa + sb[n] - 2.0f * acc[m][n][r];
                float d = sqrtf(fmaxf(s2, 0.0f) + 1e-12f);
                bool same = (ida == idb[n]);
                float pv = (same && (row != colg[n])) ? d : 0.0f;
                float nv = same ? d + BIGM : d;
                mx = fmaxf(mx, pv);
                mn = fminf(mn, nv);
            }
            #pragma unroll
            for (int o = 1; o < 16; o <<= 1) {
                mx = fmaxf(mx, __shfl_xor(mx, o));
                mn = fminf(mn, __shfl_xor(mn, o));
            }
            if ((lane & 15) == 0) {
                atomicMax(maxb + row, __float_as_int(mx));
                atomicMin(minb + row, __float_as_int(mn));
            }
        }
    }
}

__global__ void finalize_k(const int* __restrict__ maxb, const int* __restrict__ minb,
                           float* __restrict__ out) {
    int i = blockIdx.x * blockDim.x + threadIdx.x;
    if (i < B_N) {
        float z = __int_as_float(maxb[i]) - __int_as_float(minb[i]) + MARGIN;
        out[i] = fmaxf(z, 0.0f);
    }
}

extern "C" void kernel_launch(void* const* d_in, const int* in_sizes, int n_in,
                              void* d_out, int out_size, void* d_ws, size_t ws_size,
                              hipStream_t stream) {
    const float* feat = (const float*)d_in[0];
    const float* lut  = (const float*)d_in[1];
    const int*   id   = (const int*)d_in[2];
    float* out = (float*)d_out;

    // workspace layout
    char* ws = (char*)d_ws;
    ushort* featB = (ushort*)ws;                                  // 8 MiB
    ushort* oimB  = (ushort*)(ws + (size_t)B_N * D_K * 2);        // 8 MiB
    float*  sq_a  = (float*)(ws + (size_t)2 * B_N * D_K * 2);
    float*  sq_b  = sq_a + B_N;
    int*    maxb  = (int*)(sq_b + B_N);
    int*    minb  = maxb + B_N;

    prep_rows<<<B_N, 256, 0, stream>>>(feat, nullptr, featB, sq_a);
    prep_rows<<<B_N, 256, 0, stream>>>(lut, id, oimB, sq_b);
    init_minmax<<<(B_N + 255) / 256, 256, 0, stream>>>(maxb, minb);

    dim3 grid(B_N / 128, B_N / 128);
    dist_kernel<<<grid, 256, 0, stream>>>(featB, oimB, sq_a, sq_b, id, maxb, minb);

    finalize_k<<<(B_N + 255) / 256, 256, 0, stream>>>(maxb, minb, out);
}

// Round 2
// 82.916 us; speedup vs baseline: 1.0453x; 1.0453x over previous
//
#include <hip/hip_runtime.h>
#include <hip/hip_bf16.h>

// Problem constants (from reference setup_inputs)
#define B_N    4096      // batch
#define D_K    1024      // feature dim
#define MARGIN 0.3f
#define BIGM   1e5f

typedef __attribute__((ext_vector_type(8))) short short8;
typedef __attribute__((ext_vector_type(4))) float f32x4;

__device__ inline ushort f2bf(float f) {
    unsigned u = __float_as_uint(f);
    unsigned r = (u + 0x7fffu + ((u >> 16) & 1u)) >> 16;
    return (ushort)r;
}

__device__ inline void async16(const ushort* g, ushort* l) {
    __builtin_amdgcn_global_load_lds(
        (const __attribute__((address_space(1))) void*)g,
        (__attribute__((address_space(3))) void*)l,
        16, 0, 0);
}

// Fused prep: convert feat -> bf16 (blocks 0..4095) and lut[id] -> bf16
// (blocks 4096..8191), compute fp32 squared row norms, and init min/max bufs.
__global__ void prep_all(const float* __restrict__ feat,
                         const float* __restrict__ lut,
                         const int* __restrict__ id,
                         ushort* __restrict__ featB, ushort* __restrict__ oimB,
                         float* __restrict__ sq_a, float* __restrict__ sq_b,
                         int* __restrict__ maxb, int* __restrict__ minb) {
    int b = blockIdx.x;
    int t = threadIdx.x;                       // 256 threads, 4 floats each
    if (b < 16) {                              // 16*256 = 4096 entries
        int i = b * 256 + t;
        maxb[i] = 0;                           // 0.0f
        minb[i] = 0x7F800000;                  // +inf
    }
    const float* src; ushort* dst; float* sq; 
    if (b < B_N) {
        src = feat + (size_t)b * D_K;
        dst = featB + (size_t)b * D_K;
        sq  = sq_a + b;
    } else {
        int row = b - B_N;
        src = lut + (size_t)id[row] * D_K;
        dst = oimB + (size_t)row * D_K;
        sq  = sq_b + row;
    }
    float4 v = ((const float4*)src)[t];
    float ss = v.x * v.x + v.y * v.y + v.z * v.z + v.w * v.w;
    ushort4 bb;
    bb.x = f2bf(v.x); bb.y = f2bf(v.y); bb.z = f2bf(v.z); bb.w = f2bf(v.w);
    ((ushort4*)dst)[t] = bb;

    int lane = t & 63, w = t >> 6;
    #pragma unroll
    for (int o = 1; o < 64; o <<= 1) ss += __shfl_xor(ss, o);
    __shared__ float red[4];
    if (lane == 0) red[w] = ss;
    __syncthreads();
    if (t == 0) *sq = red[0] + red[1] + red[2] + red[3];
}

// Fused 128x128-tile bf16 MFMA GEMM + distance + masked per-row max/min.
// LDS layout: linear [128][32] ushort, but K-chunk XOR-swizzled:
//   linear position (row, chunk j) holds data for (row, chunk j^(row&3)).
// Achieved by pre-swizzling the global SOURCE column (global_load_lds writes
// linearly) and XOR-ing the read address the same way (rule #21).
__global__ __launch_bounds__(256)
void dist_kernel(const ushort* __restrict__ A, const ushort* __restrict__ Bm,
                 const float* __restrict__ sqa, const float* __restrict__ sqb,
                 const int* __restrict__ ids,
                 int* __restrict__ maxb, int* __restrict__ minb) {
    __shared__ ushort lA[128 * 32];
    __shared__ ushort lB[128 * 32];

    const int t = threadIdx.x;
    const int lane = t & 63;
    const int wid = t >> 6;           // 4 waves
    const int wr = wid >> 1;          // wave row (0..1)
    const int wc = wid & 1;           // wave col (0..1)
    const int rb = blockIdx.y;        // row tile
    const int cb = blockIdx.x;        // col tile
    const size_t arow0 = (size_t)rb * 128;
    const size_t brow0 = (size_t)cb * 128;

    // Staging: each wave stages 2 KiB of each tile (2 calls x 64 lanes x 16 B).
    // Linear LDS position: sidx = wid*1024 + lane*8 elements.
    //   row = sidx>>5, chunk j = (sidx>>3)&3.
    // Global source column = (j ^ (row&3)) * 8  (inverse swizzle).
    int sidx0 = wid * 1024 + lane * 8;
    int r0 = sidx0 >> 5, j0 = (sidx0 >> 3) & 3;
    int c0 = ((j0 ^ (r0 & 3)) << 3);
    int sidx1 = sidx0 + 512;
    int r1 = sidx1 >> 5, j1 = (sidx1 >> 3) & 3;
    int c1 = ((j1 ^ (r1 & 3)) << 3);
    const ushort* gA0 = A + (arow0 + r0) * D_K + c0;
    const ushort* gA1 = A + (arow0 + r1) * D_K + c1;
    const ushort* gB0 = Bm + (brow0 + r0) * D_K + c0;
    const ushort* gB1 = Bm + (brow0 + r1) * D_K + c1;
    ushort* lA_w = lA + wid * 1024;   // wave-uniform LDS base
    ushort* lB_w = lB + wid * 1024;

    // Swizzled read chunk offset (elements): row&3 == lane&3 for all fragments.
    const int xk = (((lane >> 4) ^ (lane & 3)) << 3);
    const int rA = wr * 64 + (lane & 15);   // fragment row base (+m*16)
    const int rB = wc * 64 + (lane & 15);

    f32x4 acc[4][4] = {};

    for (int k0 = 0; k0 < D_K; k0 += 32) {
        async16(gA0 + k0, lA_w);
        async16(gA1 + k0, lA_w + 512);
        async16(gB0 + k0, lB_w);
        async16(gB1 + k0, lB_w + 512);
        __syncthreads();   // drains vmcnt(0) then barrier -> tiles visible

        short8 af[4], bfr[4];
        #pragma unroll
        for (int m = 0; m < 4; m++)
            af[m] = *(const short8*)&lA[(rA + m * 16) * 32 + xk];
        #pragma unroll
        for (int n = 0; n < 4; n++)
            bfr[n] = *(const short8*)&lB[(rB + n * 16) * 32 + xk];

        #pragma unroll
        for (int m = 0; m < 4; m++)
            #pragma unroll
            for (int n = 0; n < 4; n++)
                acc[m][n] = __builtin_amdgcn_mfma_f32_16x16x32_bf16(
                    af[m], bfr[n], acc[m][n], 0, 0, 0);

        __syncthreads();   // all reads done before next stage overwrites
    }

    // Epilogue: dist + masks + per-row max/min over this block's 128 cols.
    int colg[4]; float sb[4]; int idb[4];
    #pragma unroll
    for (int n = 0; n < 4; n++) {
        int c = cb * 128 + wc * 64 + n * 16 + (lane & 15);
        colg[n] = c; sb[n] = sqb[c]; idb[n] = ids[c];
    }
    #pragma unroll
    for (int m = 0; m < 4; m++) {
        #pragma unroll
        for (int r = 0; r < 4; r++) {
            int row = rb * 128 + wr * 64 + m * 16 + (lane >> 4) * 4 + r;
            float sa = sqa[row];
            int ida = ids[row];
            float mx = 0.0f, mn = 3.0e38f;
            #pragma unroll
            for (int n = 0; n < 4; n++) {
                float s2 = sa + sb[n] - 2.0f * acc[m][n][r];
                float d = sqrtf(fmaxf(s2, 0.0f) + 1e-12f);
                bool same = (ida == idb[n]);
                float pv = (same && (row != colg[n])) ? d : 0.0f;
                float nv = same ? d + BIGM : d;
                mx = fmaxf(mx, pv);
                mn = fminf(mn, nv);
            }
            #pragma unroll
            for (int o = 1; o < 16; o <<= 1) {
                mx = fmaxf(mx, __shfl_xor(mx, o));
                mn = fminf(mn, __shfl_xor(mn, o));
            }
            if ((lane & 15) == 0) {
                atomicMax(maxb + row, __float_as_int(mx));
                atomicMin(minb + row, __float_as_int(mn));
            }
        }
    }
}

__global__ void finalize_k(const int* __restrict__ maxb, const int* __restrict__ minb,
                           float* __restrict__ out) {
    int i = blockIdx.x * blockDim.x + threadIdx.x;
    if (i < B_N) {
        float z = __int_as_float(maxb[i]) - __int_as_float(minb[i]) + MARGIN;
        out[i] = fmaxf(z, 0.0f);
    }
}

extern "C" void kernel_launch(void* const* d_in, const int* in_sizes, int n_in,
                              void* d_out, int out_size, void* d_ws, size_t ws_size,
                              hipStream_t stream) {
    const float* feat = (const float*)d_in[0];
    const float* lut  = (const float*)d_in[1];
    const int*   id   = (const int*)d_in[2];
    float* out = (float*)d_out;

    // workspace layout
    char* ws = (char*)d_ws;
    ushort* featB = (ushort*)ws;                                  // 8 MiB
    ushort* oimB  = (ushort*)(ws + (size_t)B_N * D_K * 2);        // 8 MiB
    float*  sq_a  = (float*)(ws + (size_t)2 * B_N * D_K * 2);
    float*  sq_b  = sq_a + B_N;
    int*    maxb  = (int*)(sq_b + B_N);
    int*    minb  = maxb + B_N;

    prep_all<<<2 * B_N, 256, 0, stream>>>(feat, lut, id, featB, oimB,
                                          sq_a, sq_b, maxb, minb);

    dim3 grid(B_N / 128, B_N / 128);
    dist_kernel<<<grid, 256, 0, stream>>>(featB, oimB, sq_a, sq_b, id, maxb, minb);

    finalize_k<<<(B_N + 255) / 256, 256, 0, stream>>>(maxb, minb, out);
}

// Round 3
// 75.421 us; speedup vs baseline: 1.1492x; 1.0994x over previous
//
#include <hip/hip_runtime.h>
#include <hip/hip_bf16.h>

// Problem constants (from reference setup_inputs)
#define B_N    4096      // batch
#define D_K    1024      // feature dim
#define MARGIN 0.3f
#define BIGM   1e5f

typedef __attribute__((ext_vector_type(8))) short short8;
typedef __attribute__((ext_vector_type(4))) float f32x4;

__device__ inline ushort f2bf(float f) {
    unsigned u = __float_as_uint(f);
    unsigned r = (u + 0x7fffu + ((u >> 16) & 1u)) >> 16;
    return (ushort)r;
}

__device__ inline void async16(const ushort* g, ushort* l) {
    __builtin_amdgcn_global_load_lds(
        (const __attribute__((address_space(1))) void*)g,
        (__attribute__((address_space(3))) void*)l,
        16, 0, 0);
}

// Fused prep: convert feat -> bf16 (blocks 0..4095) and lut[id] -> bf16
// (blocks 4096..8191), compute fp32 squared row norms, and init min/max bufs.
__global__ void prep_all(const float* __restrict__ feat,
                         const float* __restrict__ lut,
                         const int* __restrict__ id,
                         ushort* __restrict__ featB, ushort* __restrict__ oimB,
                         float* __restrict__ sq_a, float* __restrict__ sq_b,
                         int* __restrict__ maxb, int* __restrict__ minb) {
    int b = blockIdx.x;
    int t = threadIdx.x;                       // 256 threads, 4 floats each
    if (b < 16) {                              // 16*256 = 4096 entries
        int i = b * 256 + t;
        maxb[i] = 0;                           // 0.0f
        minb[i] = 0x7F800000;                  // +inf
    }
    const float* src; ushort* dst; float* sq;
    if (b < B_N) {
        src = feat + (size_t)b * D_K;
        dst = featB + (size_t)b * D_K;
        sq  = sq_a + b;
    } else {
        int row = b - B_N;
        src = lut + (size_t)id[row] * D_K;
        dst = oimB + (size_t)row * D_K;
        sq  = sq_b + row;
    }
    float4 v = ((const float4*)src)[t];
    float ss = v.x * v.x + v.y * v.y + v.z * v.z + v.w * v.w;
    ushort4 bb;
    bb.x = f2bf(v.x); bb.y = f2bf(v.y); bb.z = f2bf(v.z); bb.w = f2bf(v.w);
    ((ushort4*)dst)[t] = bb;

    int lane = t & 63, w = t >> 6;
    #pragma unroll
    for (int o = 1; o < 64; o <<= 1) ss += __shfl_xor(ss, o);
    __shared__ float red[4];
    if (lane == 0) red[w] = ss;
    __syncthreads();
    if (t == 0) *sq = red[0] + red[1] + red[2] + red[3];
}

// 256x256-tile bf16 MFMA GEMM, 2-phase double-buffered LDS (T3-min recipe,
// counted vmcnt), fused distance + masked per-row max/min epilogue.
// 8 waves as 2(M) x 4(N); per-wave output 128x64; BK=32; LDS = 64 KiB.
__global__ __launch_bounds__(512, 2)
void dist_kernel(const ushort* __restrict__ A, const ushort* __restrict__ Bm,
                 const float* __restrict__ sqa, const float* __restrict__ sqb,
                 const int* __restrict__ ids,
                 int* __restrict__ maxb, int* __restrict__ minb) {
    __shared__ ushort lA[2][256 * 32];
    __shared__ ushort lB[2][256 * 32];

    const int t = threadIdx.x;
    const int lane = t & 63;
    const int wid = t >> 6;          // 8 waves
    const int wr = wid >> 2;         // 0..1 (M)
    const int wc = wid & 3;          // 0..3 (N)
    const int l15 = lane & 15;
    const int h = lane >> 4;
    const int rb = blockIdx.y, cb = blockIdx.x;

    // Staging addresses: whole block stages 256x32 tile in 2 rounds of
    // 512 thr x 16B. Round 0 covers rows 0..127, round 1 rows 128..255.
    const int e0 = wid * 512 + lane * 8;       // element idx in tile, round 0
    const int r0 = e0 >> 5, c0 = e0 & 31;
    const ushort* gA0 = A  + (size_t)(rb * 256 + r0) * D_K + c0;
    const ushort* gB0 = Bm + (size_t)(cb * 256 + r0) * D_K + c0;
    ushort* dA0 = &lA[0][wid * 512];           // lane*16B offset is implicit
    ushort* dB0 = &lB[0][wid * 512];

    // Fragment read offsets (elements) within a 256x32 buffer.
    const int aoff = (wr * 128 + l15) * 32 + h * 8;   // + m*512
    const int boff = (wc * 64  + l15) * 32 + h * 8;   // + n*512

    f32x4 acc[8][4] = {};

    // prologue: stage K-step 0 into buffer 0
    async16(gA0,             dA0);
    async16(gA0 + 128 * D_K, dA0 + 4096);
    async16(gB0,             dB0);
    async16(gB0 + 128 * D_K, dB0 + 4096);

    for (int kt = 0; kt < 32; ++kt) {
        const int s = kt & 1;
        if (kt < 31) {
            // issue next K-step into the other buffer; keep it in flight
            const ushort* ga = gA0 + (kt + 1) * 32;
            const ushort* gb = gB0 + (kt + 1) * 32;
            ushort* da = dA0 + (s ^ 1) * 8192;
            ushort* db = dB0 + (s ^ 1) * 8192;
            async16(ga,             da);
            async16(ga + 128 * D_K, da + 4096);
            async16(gb,             db);
            async16(gb + 128 * D_K, db + 4096);
            asm volatile("s_waitcnt vmcnt(4)" ::: "memory");  // cur landed, next in flight
        } else {
            asm volatile("s_waitcnt vmcnt(0)" ::: "memory");
        }
        __builtin_amdgcn_sched_barrier(0);
        __builtin_amdgcn_s_barrier();      // all waves' cur-tile data visible

        short8 af[8], bfr[4];
        const ushort* pa = &lA[0][0] + s * 8192 + aoff;
        const ushort* pb = &lB[0][0] + s * 8192 + boff;
        #pragma unroll
        for (int m = 0; m < 8; m++) af[m] = *(const short8*)(pa + m * 512);
        #pragma unroll
        for (int n = 0; n < 4; n++) bfr[n] = *(const short8*)(pb + n * 512);

        #pragma unroll
        for (int m = 0; m < 8; m++)
            #pragma unroll
            for (int n = 0; n < 4; n++)
                acc[m][n] = __builtin_amdgcn_mfma_f32_16x16x32_bf16(
                    af[m], bfr[n], acc[m][n], 0, 0, 0);

        __builtin_amdgcn_s_barrier();      // reads done before buffer reuse
    }

    // Epilogue: dist + masks + per-row max/min over this block's 256 cols.
    int colg[4]; float sb[4]; int idb[4];
    #pragma unroll
    for (int n = 0; n < 4; n++) {
        int c = cb * 256 + wc * 64 + n * 16 + l15;
        colg[n] = c; sb[n] = sqb[c]; idb[n] = ids[c];
    }
    #pragma unroll
    for (int m = 0; m < 8; m++) {
        #pragma unroll
        for (int r = 0; r < 4; r++) {
            int row = rb * 256 + wr * 128 + m * 16 + h * 4 + r;
            float sa = sqa[row];
            int ida = ids[row];
            float mx = 0.0f, mn = 3.0e38f;
            #pragma unroll
            for (int n = 0; n < 4; n++) {
                float s2 = sa + sb[n] - 2.0f * acc[m][n][r];
                float d = sqrtf(fmaxf(s2, 0.0f) + 1e-12f);
                bool same = (ida == idb[n]);
                float pv = (same && (row != colg[n])) ? d : 0.0f;
                float nv = same ? d + BIGM : d;
                mx = fmaxf(mx, pv);
                mn = fminf(mn, nv);
            }
            #pragma unroll
            for (int o = 1; o < 16; o <<= 1) {
                mx = fmaxf(mx, __shfl_xor(mx, o));
                mn = fminf(mn, __shfl_xor(mn, o));
            }
            if (l15 == 0) {
                atomicMax(maxb + row, __float_as_int(mx));
                atomicMin(minb + row, __float_as_int(mn));
            }
        }
    }
}

__global__ void finalize_k(const int* __restrict__ maxb, const int* __restrict__ minb,
                           float* __restrict__ out) {
    int i = blockIdx.x * blockDim.x + threadIdx.x;
    if (i < B_N) {
        float z = __int_as_float(maxb[i]) - __int_as_float(minb[i]) + MARGIN;
        out[i] = fmaxf(z, 0.0f);
    }
}

extern "C" void kernel_launch(void* const* d_in, const int* in_sizes, int n_in,
                              void* d_out, int out_size, void* d_ws, size_t ws_size,
                              hipStream_t stream) {
    const float* feat = (const float*)d_in[0];
    const float* lut  = (const float*)d_in[1];
    const int*   id   = (const int*)d_in[2];
    float* out = (float*)d_out;

    // workspace layout
    char* ws = (char*)d_ws;
    ushort* featB = (ushort*)ws;                                  // 8 MiB
    ushort* oimB  = (ushort*)(ws + (size_t)B_N * D_K * 2);        // 8 MiB
    float*  sq_a  = (float*)(ws + (size_t)2 * B_N * D_K * 2);
    float*  sq_b  = sq_a + B_N;
    int*    maxb  = (int*)(sq_b + B_N);
    int*    minb  = maxb + B_N;

    prep_all<<<2 * B_N, 256, 0, stream>>>(feat, lut, id, featB, oimB,
                                          sq_a, sq_b, maxb, minb);

    dim3 grid(B_N / 256, B_N / 256);
    dist_kernel<<<grid, 512, 0, stream>>>(featB, oimB, sq_a, sq_b, id, maxb, minb);

    finalize_k<<<(B_N + 255) / 256, 256, 0, stream>>>(maxb, minb, out);
}

// Round 4
// 70.196 us; speedup vs baseline: 1.2347x; 1.0744x over previous
//
#include <hip/hip_runtime.h>
#include <hip/hip_bf16.h>

// Problem constants (from reference setup_inputs)
#define B_N    4096      // batch
#define D_K    1024      // feature dim
#define MARGIN 0.3f
#define BIGM   1e5f

typedef __attribute__((ext_vector_type(8))) short short8;
typedef __attribute__((ext_vector_type(4))) float f32x4;

__device__ inline ushort f2bf(float f) {
    unsigned u = __float_as_uint(f);
    unsigned r = (u + 0x7fffu + ((u >> 16) & 1u)) >> 16;
    return (ushort)r;
}

__device__ inline void async16(const ushort* g, ushort* l) {
    __builtin_amdgcn_global_load_lds(
        (const __attribute__((address_space(1))) void*)g,
        (__attribute__((address_space(3))) void*)l,
        16, 0, 0);
}

// Fused prep: convert feat -> bf16 (blocks 0..4095) and lut[id] -> bf16
// (blocks 4096..8191), compute fp32 squared row norms, and init min/max bufs.
__global__ void prep_all(const float* __restrict__ feat,
                         const float* __restrict__ lut,
                         const int* __restrict__ id,
                         ushort* __restrict__ featB, ushort* __restrict__ oimB,
                         float* __restrict__ sq_a, float* __restrict__ sq_b,
                         int* __restrict__ maxb, int* __restrict__ minb) {
    int b = blockIdx.x;
    int t = threadIdx.x;                       // 256 threads, 4 floats each
    if (b < 16) {                              // 16*256 = 4096 entries
        int i = b * 256 + t;
        maxb[i] = 0;                           // 0.0f
        minb[i] = 0x7F800000;                  // +inf
    }
    const float* src; ushort* dst; float* sq;
    if (b < B_N) {
        src = feat + (size_t)b * D_K;
        dst = featB + (size_t)b * D_K;
        sq  = sq_a + b;
    } else {
        int row = b - B_N;
        src = lut + (size_t)id[row] * D_K;
        dst = oimB + (size_t)row * D_K;
        sq  = sq_b + row;
    }
    float4 v = ((const float4*)src)[t];
    float ss = v.x * v.x + v.y * v.y + v.z * v.z + v.w * v.w;
    ushort4 bb;
    bb.x = f2bf(v.x); bb.y = f2bf(v.y); bb.z = f2bf(v.z); bb.w = f2bf(v.w);
    ((ushort4*)dst)[t] = bb;

    int lane = t & 63, w = t >> 6;
    #pragma unroll
    for (int o = 1; o < 64; o <<= 1) ss += __shfl_xor(ss, o);
    __shared__ float red[4];
    if (lane == 0) red[w] = ss;
    __syncthreads();
    if (t == 0) *sq = red[0] + red[1] + red[2] + red[3];
}

// 256x256-tile bf16 MFMA GEMM, 8-phase-style schedule (T3+T4+T2+T5):
// BK=64, 4 phases per K-tile (one C-quadrant = 16 MFMA each), double-buffered
// 128 KiB LDS, counted vmcnt(2) once per K-tile, chunk-XOR bank swizzle
// (j ^= row&7 at 16B granularity; pre-swizzled global src + swizzled read).
// 8 waves 2(M)x4(N); per-wave output 128x64. Fused distance epilogue.
__global__ __launch_bounds__(512, 2)
void dist_kernel(const ushort* __restrict__ A, const ushort* __restrict__ Bm,
                 const float* __restrict__ sqa, const float* __restrict__ sqb,
                 const int* __restrict__ ids,
                 int* __restrict__ maxb, int* __restrict__ minb) {
    __shared__ ushort lA[2][256 * 64];   // 32 KB per buffer
    __shared__ ushort lB[2][256 * 64];

    const int t = threadIdx.x;
    const int lane = t & 63;
    const int wid = t >> 6;          // 8 waves
    const int wr = wid >> 2;         // 0..1 (M)
    const int wc = wid & 3;          // 0..3 (N)
    const int l15 = lane & 15;
    const int h = lane >> 4;
    const int rb = blockIdx.y, cb = blockIdx.x;

    // ---- staging slots: 8 x (512 thr x 16B). q<4 = A tile, q>=4 = B tile.
    // LDS linear elem = (q&3)*4096 + t*8; row = elem>>6, chunk j=(elem>>3)&7.
    // Global source chunk = j ^ (row&7)  (inverse of the read swizzle).
    const ushort* gq[8];
    #pragma unroll
    for (int q = 0; q < 8; q++) {
        int elem = (q & 3) * 4096 + t * 8;
        int r = elem >> 6;
        int j = (elem >> 3) & 7;
        int col = (j ^ (r & 7)) << 3;
        gq[q] = (q < 4) ? (A  + (size_t)(rb * 256 + r) * D_K + col)
                        : (Bm + (size_t)(cb * 256 + r) * D_K + col);
    }
    const int lds_wo = wid * 512;    // wave-uniform lane-block offset (elems)

    // ---- fragment read offsets (elements), swizzled chunk per ks
    const int q7 = l15 & 7;
    const int xs0 = ((h)     ^ q7) << 3;     // ks=0 chunk
    const int xs1 = ((h + 4) ^ q7) << 3;     // ks=1 chunk
    const int arow = (wr * 128 + l15) * 64;  // + mh*4096 + mf*1024
    const int brow = (wc * 64  + l15) * 64;  // + nh*2048 + nf*1024

    f32x4 acc[8][4] = {};
    short8 af[4][2];        // current mh quadrant
    short8 bfr[2][2][2];    // [nh][nf][ks], both held

    // ---- prologue: stage K-tile 0 into buffer 0
    #pragma unroll
    for (int q = 0; q < 8; q++) {
        ushort* dst = ((q < 4) ? &lA[0][0] : &lB[0][0]) + (q & 3) * 4096 + lds_wo;
        async16(gq[q], dst);
    }

    #pragma unroll 2
    for (int kt = 0; kt < 16; ++kt) {
        const int s = kt & 1;
        const ushort* rA = &lA[s][0];
        const ushort* rB = &lB[s][0];
        ushort* wA = &lA[s ^ 1][0];
        ushort* wB = &lB[s ^ 1][0];
        const int nc = (kt + 1) * 64;
        const bool more = (kt < 15);

        // ---------- P0: quadrant (mh0, nh0) ----------
        if (more) {
            async16(gq[0] + nc, wA + 0 * 4096 + lds_wo);
            async16(gq[1] + nc, wA + 1 * 4096 + lds_wo);
            asm volatile("s_waitcnt vmcnt(2)" ::: "memory");  // cur tile landed
        } else {
            asm volatile("s_waitcnt vmcnt(0)" ::: "memory");
        }
        __builtin_amdgcn_sched_barrier(0);
        __builtin_amdgcn_s_barrier();
        #pragma unroll
        for (int mf = 0; mf < 4; mf++) {
            af[mf][0] = *(const short8*)(rA + arow + mf * 1024 + xs0);
            af[mf][1] = *(const short8*)(rA + arow + mf * 1024 + xs1);
        }
        #pragma unroll
        for (int nf = 0; nf < 2; nf++) {
            bfr[0][nf][0] = *(const short8*)(rB + brow + nf * 1024 + xs0);
            bfr[0][nf][1] = *(const short8*)(rB + brow + nf * 1024 + xs1);
        }
        __builtin_amdgcn_sched_barrier(0);
        __builtin_amdgcn_s_setprio(1);
        #pragma unroll
        for (int mf = 0; mf < 4; mf++)
            #pragma unroll
            for (int nf = 0; nf < 2; nf++) {
                acc[mf][nf] = __builtin_amdgcn_mfma_f32_16x16x32_bf16(
                    af[mf][0], bfr[0][nf][0], acc[mf][nf], 0, 0, 0);
                acc[mf][nf] = __builtin_amdgcn_mfma_f32_16x16x32_bf16(
                    af[mf][1], bfr[0][nf][1], acc[mf][nf], 0, 0, 0);
            }
        __builtin_amdgcn_s_setprio(0);
        __builtin_amdgcn_sched_barrier(0);
        __builtin_amdgcn_s_barrier();

        // ---------- P1: quadrant (mh0, nh1) ----------
        #pragma unroll
        for (int nf = 0; nf < 2; nf++) {
            bfr[1][nf][0] = *(const short8*)(rB + brow + 2048 + nf * 1024 + xs0);
            bfr[1][nf][1] = *(const short8*)(rB + brow + 2048 + nf * 1024 + xs1);
        }
        if (more) {
            async16(gq[2] + nc, wA + 2 * 4096 + lds_wo);
            async16(gq[3] + nc, wA + 3 * 4096 + lds_wo);
        }
        __builtin_amdgcn_sched_barrier(0);
        __builtin_amdgcn_s_barrier();
        __builtin_amdgcn_s_setprio(1);
        #pragma unroll
        for (int mf = 0; mf < 4; mf++)
            #pragma unroll
            for (int nf = 0; nf < 2; nf++) {
                acc[mf][2 + nf] = __builtin_amdgcn_mfma_f32_16x16x32_bf16(
                    af[mf][0], bfr[1][nf][0], acc[mf][2 + nf], 0, 0, 0);
                acc[mf][2 + nf] = __builtin_amdgcn_mfma_f32_16x16x32_bf16(
                    af[mf][1], bfr[1][nf][1], acc[mf][2 + nf], 0, 0, 0);
            }
        __builtin_amdgcn_s_setprio(0);
        __builtin_amdgcn_sched_barrier(0);
        __builtin_amdgcn_s_barrier();

        // ---------- P2: quadrant (mh1, nh1) ----------
        #pragma unroll
        for (int mf = 0; mf < 4; mf++) {
            af[mf][0] = *(const short8*)(rA + arow + 4096 + mf * 1024 + xs0);
            af[mf][1] = *(const short8*)(rA + arow + 4096 + mf * 1024 + xs1);
        }
        if (more) {
            async16(gq[4] + nc, wB + 0 * 4096 + lds_wo);
            async16(gq[5] + nc, wB + 1 * 4096 + lds_wo);
        }
        __builtin_amdgcn_sched_barrier(0);
        __builtin_amdgcn_s_barrier();
        __builtin_amdgcn_s_setprio(1);
        #pragma unroll
        for (int mf = 0; mf < 4; mf++)
            #pragma unroll
            for (int nf = 0; nf < 2; nf++) {
                acc[4 + mf][2 + nf] = __builtin_amdgcn_mfma_f32_16x16x32_bf16(
                    af[mf][0], bfr[1][nf][0], acc[4 + mf][2 + nf], 0, 0, 0);
                acc[4 + mf][2 + nf] = __builtin_amdgcn_mfma_f32_16x16x32_bf16(
                    af[mf][1], bfr[1][nf][1], acc[4 + mf][2 + nf], 0, 0, 0);
            }
        __builtin_amdgcn_s_setprio(0);
        __builtin_amdgcn_sched_barrier(0);
        __builtin_amdgcn_s_barrier();

        // ---------- P3: quadrant (mh1, nh0) ----------
        if (more) {
            async16(gq[6] + nc, wB + 2 * 4096 + lds_wo);
            async16(gq[7] + nc, wB + 3 * 4096 + lds_wo);
        }
        __builtin_amdgcn_sched_barrier(0);
        __builtin_amdgcn_s_barrier();
        __builtin_amdgcn_s_setprio(1);
        #pragma unroll
        for (int mf = 0; mf < 4; mf++)
            #pragma unroll
            for (int nf = 0; nf < 2; nf++) {
                acc[4 + mf][nf] = __builtin_amdgcn_mfma_f32_16x16x32_bf16(
                    af[mf][0], bfr[0][nf][0], acc[4 + mf][nf], 0, 0, 0);
                acc[4 + mf][nf] = __builtin_amdgcn_mfma_f32_16x16x32_bf16(
                    af[mf][1], bfr[0][nf][1], acc[4 + mf][nf], 0, 0, 0);
            }
        __builtin_amdgcn_s_setprio(0);
        __builtin_amdgcn_sched_barrier(0);
        __builtin_amdgcn_s_barrier();
    }

    // Epilogue: dist + masks + per-row max/min over this block's 256 cols.
    int colg[4]; float sb[4]; int idb[4];
    #pragma unroll
    for (int n = 0; n < 4; n++) {
        int c = cb * 256 + wc * 64 + n * 16 + l15;
        colg[n] = c; sb[n] = sqb[c]; idb[n] = ids[c];
    }
    #pragma unroll
    for (int m = 0; m < 8; m++) {
        #pragma unroll
        for (int r = 0; r < 4; r++) {
            int row = rb * 256 + wr * 128 + m * 16 + h * 4 + r;
            float sa = sqa[row];
            int ida = ids[row];
            float mx = 0.0f, mn = 3.0e38f;
            #pragma unroll
            for (int n = 0; n < 4; n++) {
                float s2 = sa + sb[n] - 2.0f * acc[m][n][r];
                float d = sqrtf(fmaxf(s2, 0.0f) + 1e-12f);
                bool same = (ida == idb[n]);
                float pv = (same && (row != colg[n])) ? d : 0.0f;
                float nv = same ? d + BIGM : d;
                mx = fmaxf(mx, pv);
                mn = fminf(mn, nv);
            }
            #pragma unroll
            for (int o = 1; o < 16; o <<= 1) {
                mx = fmaxf(mx, __shfl_xor(mx, o));
                mn = fminf(mn, __shfl_xor(mn, o));
            }
            if (l15 == 0) {
                atomicMax(maxb + row, __float_as_int(mx));
                atomicMin(minb + row, __float_as_int(mn));
            }
        }
    }
}

__global__ void finalize_k(const int* __restrict__ maxb, const int* __restrict__ minb,
                           float* __restrict__ out) {
    int i = blockIdx.x * blockDim.x + threadIdx.x;
    if (i < B_N) {
        float z = __int_as_float(maxb[i]) - __int_as_float(minb[i]) + MARGIN;
        out[i] = fmaxf(z, 0.0f);
    }
}

extern "C" void kernel_launch(void* const* d_in, const int* in_sizes, int n_in,
                              void* d_out, int out_size, void* d_ws, size_t ws_size,
                              hipStream_t stream) {
    const float* feat = (const float*)d_in[0];
    const float* lut  = (const float*)d_in[1];
    const int*   id   = (const int*)d_in[2];
    float* out = (float*)d_out;

    // workspace layout
    char* ws = (char*)d_ws;
    ushort* featB = (ushort*)ws;                                  // 8 MiB
    ushort* oimB  = (ushort*)(ws + (size_t)B_N * D_K * 2);        // 8 MiB
    float*  sq_a  = (float*)(ws + (size_t)2 * B_N * D_K * 2);
    float*  sq_b  = sq_a + B_N;
    int*    maxb  = (int*)(sq_b + B_N);
    int*    minb  = maxb + B_N;

    prep_all<<<2 * B_N, 256, 0, stream>>>(feat, lut, id, featB, oimB,
                                          sq_a, sq_b, maxb, minb);

    dim3 grid(B_N / 256, B_N / 256);
    dist_kernel<<<grid, 512, 0, stream>>>(featB, oimB, sq_a, sq_b, id, maxb, minb);

    finalize_k<<<(B_N + 255) / 256, 256, 0, stream>>>(maxb, minb, out);
}